// Round 1
// baseline (227.105 us; speedup 1.0000x reference)
//
#include <hip/hip_runtime.h>

#define HH 128
#define KT 32
#define RT 64

// ---------------- projection GEMM: P[r][c] = sum_k Z[r][k] * W[k][c] ----------------
// block = 256 threads; tile = 64 rows x 128 cols; thread tile = 4 rows x 8 cols.
__global__ __launch_bounds__(256) void project_kernel(
    const float* __restrict__ Z, const float* __restrict__ W,
    float* __restrict__ P, int nrows)
{
    __shared__ float sW[KT][HH];       // 16 KB
    __shared__ float sZ[RT][KT + 4];   // 9 KB (pad 4 floats: kills 4-way bank conflict, keeps 16B align)

    const int t  = threadIdx.x;
    const int c0 = (t & 15) * 8;       // 16 col-groups of 8
    const int r0 = (t >> 4) * 4;       // 16 row-groups of 4

    for (int rbase = blockIdx.x * RT; rbase < nrows; rbase += gridDim.x * RT) {
        float acc[4][8];
        #pragma unroll
        for (int a = 0; a < 4; ++a)
            #pragma unroll
            for (int b = 0; b < 8; ++b) acc[a][b] = 0.f;

        for (int kt = 0; kt < HH; kt += KT) {
            __syncthreads();
            // stage W[kt..kt+31][:]  (1024 float4, 4 per thread)
            {
                const float4* Wg = (const float4*)(W + (size_t)kt * HH);
                float4* sW4 = (float4*)&sW[0][0];
                #pragma unroll
                for (int i = 0; i < 4; ++i) sW4[t + i * 256] = Wg[t + i * 256];
            }
            // stage Z[rbase..rbase+63][kt..kt+31]  (512 float4, 2 per thread)
            #pragma unroll
            for (int i = 0; i < 2; ++i) {
                int idx = t + i * 256;     // 0..511
                int r   = idx >> 3;        // 0..63
                int kc  = idx & 7;         // float4 chunk within 32 k
                int rr  = rbase + r;
                float4 zv = make_float4(0.f, 0.f, 0.f, 0.f);
                if (rr < nrows) zv = *(const float4*)(Z + (size_t)rr * HH + kt + kc * 4);
                *(float4*)&sZ[r][kc * 4] = zv;
            }
            __syncthreads();

            #pragma unroll 8
            for (int kr = 0; kr < KT; ++kr) {
                float4 w0 = *(const float4*)&sW[kr][c0];
                float4 w1 = *(const float4*)&sW[kr][c0 + 4];
                float wv[8] = {w0.x, w0.y, w0.z, w0.w, w1.x, w1.y, w1.z, w1.w};
                float zv[4] = {sZ[r0 + 0][kr], sZ[r0 + 1][kr], sZ[r0 + 2][kr], sZ[r0 + 3][kr]};
                #pragma unroll
                for (int a = 0; a < 4; ++a)
                    #pragma unroll
                    for (int b = 0; b < 8; ++b)
                        acc[a][b] = fmaf(zv[a], wv[b], acc[a][b]);
            }
        }
        #pragma unroll
        for (int a = 0; a < 4; ++a) {
            int rr = rbase + r0 + a;
            if (rr < nrows) {
                *(float4*)(P + (size_t)rr * HH + c0)     = make_float4(acc[a][0], acc[a][1], acc[a][2], acc[a][3]);
                *(float4*)(P + (size_t)rr * HH + c0 + 4) = make_float4(acc[a][4], acc[a][5], acc[a][6], acc[a][7]);
            }
        }
    }
}

// ---------------- edge kernel: out[e] = relu(Pu[u]+Pi[i]+b1) . W2 + b2 ----------------
// one 32-lane group per edge; each lane owns 4 contiguous channels (float4).
__global__ __launch_bounds__(256) void edge_kernel(
    const float* __restrict__ Pu, const float* __restrict__ Pi,
    const int* __restrict__ row, const int* __restrict__ col,
    const float* __restrict__ b1, const float* __restrict__ W2,
    const float* __restrict__ b2, float* __restrict__ out, int E)
{
    const int lane   = threadIdx.x & 31;
    const int gid    = (blockIdx.x * blockDim.x + threadIdx.x) >> 5;
    const int stride = (gridDim.x * blockDim.x) >> 5;
    const int c0     = lane * 4;

    const float4 b1v = *(const float4*)(b1 + c0);
    const float4 w2v = *(const float4*)(W2 + c0);
    const float  b2s = b2[0];

    for (int e = gid; e < E; e += stride) {
        int u  = row[e];
        int it = col[e];
        float4 pu = *(const float4*)(Pu + (size_t)u  * HH + c0);
        float4 pi = *(const float4*)(Pi + (size_t)it * HH + c0);
        float h0 = fmaxf(pu.x + pi.x + b1v.x, 0.f);
        float h1 = fmaxf(pu.y + pi.y + b1v.y, 0.f);
        float h2 = fmaxf(pu.z + pi.z + b1v.z, 0.f);
        float h3 = fmaxf(pu.w + pi.w + b1v.w, 0.f);
        float p = h0 * w2v.x;
        p = fmaf(h1, w2v.y, p);
        p = fmaf(h2, w2v.z, p);
        p = fmaf(h3, w2v.w, p);
        #pragma unroll
        for (int m = 16; m >= 1; m >>= 1)
            p += __shfl_xor(p, m, 64);
        if (lane == 0) out[e] = p + b2s;
    }
}

// ---------------- fallback (no workspace): direct per-edge compute ----------------
__global__ __launch_bounds__(256) void edge_direct_kernel(
    const float* __restrict__ zu, const float* __restrict__ zi,
    const int* __restrict__ row, const int* __restrict__ col,
    const float* __restrict__ W1, const float* __restrict__ b1,
    const float* __restrict__ W2, const float* __restrict__ b2,
    float* __restrict__ out, int E)
{
    const int lane   = threadIdx.x & 31;
    const int gid    = (blockIdx.x * blockDim.x + threadIdx.x) >> 5;
    const int stride = (gridDim.x * blockDim.x) >> 5;
    const int c0     = lane * 4;

    const float4 b1v = *(const float4*)(b1 + c0);
    const float4 w2v = *(const float4*)(W2 + c0);
    const float  b2s = b2[0];

    for (int e = gid; e < E; e += stride) {
        int u  = row[e];
        int it = col[e];
        const float* zur = zu + (size_t)u  * HH;
        const float* zir = zi + (size_t)it * HH;
        float4 acc = b1v;
        for (int k = 0; k < HH; ++k) {
            float  zk = zur[k];
            float4 w  = *(const float4*)(W1 + (size_t)k * HH + c0);
            acc.x = fmaf(zk, w.x, acc.x);
            acc.y = fmaf(zk, w.y, acc.y);
            acc.z = fmaf(zk, w.z, acc.z);
            acc.w = fmaf(zk, w.w, acc.w);
        }
        for (int k = 0; k < HH; ++k) {
            float  zk = zir[k];
            float4 w  = *(const float4*)(W1 + (size_t)(HH + k) * HH + c0);
            acc.x = fmaf(zk, w.x, acc.x);
            acc.y = fmaf(zk, w.y, acc.y);
            acc.z = fmaf(zk, w.z, acc.z);
            acc.w = fmaf(zk, w.w, acc.w);
        }
        float h0 = fmaxf(acc.x, 0.f);
        float h1 = fmaxf(acc.y, 0.f);
        float h2 = fmaxf(acc.z, 0.f);
        float h3 = fmaxf(acc.w, 0.f);
        float p = h0 * w2v.x;
        p = fmaf(h1, w2v.y, p);
        p = fmaf(h2, w2v.z, p);
        p = fmaf(h3, w2v.w, p);
        #pragma unroll
        for (int m = 16; m >= 1; m >>= 1)
            p += __shfl_xor(p, m, 64);
        if (lane == 0) out[e] = p + b2s;
    }
}

extern "C" void kernel_launch(void* const* d_in, const int* in_sizes, int n_in,
                              void* d_out, int out_size, void* d_ws, size_t ws_size,
                              hipStream_t stream)
{
    const float* z_user = (const float*)d_in[0];
    const float* z_item = (const float*)d_in[1];
    const int*   row    = (const int*)d_in[2];
    const int*   col    = (const int*)d_in[3];
    const float* W1     = (const float*)d_in[4];
    const float* b1     = (const float*)d_in[5];
    const float* W2     = (const float*)d_in[6];
    const float* b2     = (const float*)d_in[7];
    float*       out    = (float*)d_out;

    const int n_user = in_sizes[0] / HH;
    const int n_item = in_sizes[1] / HH;
    const int E      = in_sizes[2];

    const size_t need = ((size_t)n_user + (size_t)n_item) * HH * sizeof(float);
    if (ws_size >= need) {
        float* Pu = (float*)d_ws;
        float* Pi = Pu + (size_t)n_user * HH;
        project_kernel<<<(n_user + RT - 1) / RT, 256, 0, stream>>>(z_user, W1, Pu, n_user);
        project_kernel<<<(n_item + RT - 1) / RT, 256, 0, stream>>>(z_item, W1 + HH * HH, Pi, n_item);
        edge_kernel<<<2048, 256, 0, stream>>>(Pu, Pi, row, col, b1, W2, b2, out, E);
    } else {
        edge_direct_kernel<<<2048, 256, 0, stream>>>(z_user, z_item, row, col, W1, b1, W2, b2, out, E);
    }
}

// Round 2
// 112.692 us; speedup vs baseline: 2.0153x; 2.0153x over previous
//
#include <hip/hip_runtime.h>

#define HH 128

typedef __attribute__((ext_vector_type(8))) short bf16x8;
typedef __attribute__((ext_vector_type(4))) float f32x4;

__device__ inline unsigned short f2bf(float f) {
    unsigned u = __builtin_bit_cast(unsigned, f);
    u += 0x7FFF + ((u >> 16) & 1);   // round to nearest even
    return (unsigned short)(u >> 16);
}
__device__ inline float bf2f(unsigned short h) {
    return __builtin_bit_cast(float, (unsigned)h << 16);
}

// ---------------- MFMA projection: P[r][c] = bf16( sum_k Z[r][k]*W[k][c] + bias[c] ) ----------
// block = 256 threads (4 waves). Block tile = 64 rows x 128 cols, K = 128.
// W^T staged once per block in LDS (bf16, chunk-XOR swizzled); grid-stride over row tiles.
__global__ __launch_bounds__(256) void project_mfma_kernel(
    const float* __restrict__ Z, const float* __restrict__ W,
    const float* __restrict__ bias, int addBias,
    unsigned short* __restrict__ P, int nrows)
{
    // sWt: element (c,k) at c*128 + ((k>>3)^(c&15))*8 + (k&7)   (ushort)
    __shared__ unsigned short sWt[128 * 128];    // 32 KB
    __shared__ unsigned short sOut[64 * 136];    // 17 KB, stride 136 (272B = 17*16B)

    const int t    = threadIdx.x;
    const int wave = t >> 6;
    const int lane = t & 63;
    const int l16  = lane & 15;
    const int lk8  = (lane >> 4) * 8;

    // ---- stage W^T as bf16 with chunk swizzle ----
    #pragma unroll 4
    for (int i = 0; i < 16; ++i) {
        int idx = t + i * 256;          // 0..4095 float4 chunks of W
        int k   = idx >> 5;             // 128 k-rows, 32 float4 each
        int c4  = (idx & 31) * 4;
        float4 w = *(const float4*)(W + (size_t)k * HH + c4);
        float wv[4] = {w.x, w.y, w.z, w.w};
        #pragma unroll
        for (int j = 0; j < 4; ++j) {
            int c = c4 + j;
            sWt[c * 128 + (((k >> 3) ^ (c & 15)) << 3) + (k & 7)] = f2bf(wv[j]);
        }
    }

    // per-lane bias values (col = nt*16 + l16)
    float b1r[8];
    #pragma unroll
    for (int nt = 0; nt < 8; ++nt)
        b1r[nt] = addBias ? bias[nt * 16 + l16] : 0.f;

    __syncthreads();

    const int ntiles = (nrows + 63) >> 6;
    for (int tile = blockIdx.x; tile < ntiles; tile += gridDim.x) {
        const int rbase = tile << 6;

        f32x4 acc[8];
        #pragma unroll
        for (int nt = 0; nt < 8; ++nt) acc[nt] = (f32x4)0.f;

        int m = rbase + wave * 16 + l16;
        if (m > nrows - 1) m = nrows - 1;          // clamp tail (stores guarded)
        const float* Zrow = Z + (size_t)m * HH;

        #pragma unroll
        for (int kk = 0; kk < 4; ++kk) {
            // A fragment: 8 contiguous floats -> bf16
            float4 z0 = *(const float4*)(Zrow + kk * 32 + lk8);
            float4 z1 = *(const float4*)(Zrow + kk * 32 + lk8 + 4);
            bf16x8 a;
            a[0] = (short)f2bf(z0.x); a[1] = (short)f2bf(z0.y);
            a[2] = (short)f2bf(z0.z); a[3] = (short)f2bf(z0.w);
            a[4] = (short)f2bf(z1.x); a[5] = (short)f2bf(z1.y);
            a[6] = (short)f2bf(z1.z); a[7] = (short)f2bf(z1.w);

            const int chunkSw = ((kk * 4 + (lane >> 4)) ^ l16) << 3;
            #pragma unroll
            for (int nt = 0; nt < 8; ++nt) {
                int c = nt * 16 + l16;
                bf16x8 b = *(const bf16x8*)(sWt + c * 128 + chunkSw);
                acc[nt] = __builtin_amdgcn_mfma_f32_16x16x32_bf16(a, b, acc[nt], 0, 0, 0);
            }
        }

        __syncthreads();   // sOut safe to overwrite
        #pragma unroll
        for (int nt = 0; nt < 8; ++nt) {
            int colc = nt * 16 + l16;
            #pragma unroll
            for (int r = 0; r < 4; ++r) {
                int orow = wave * 16 + (lane >> 4) * 4 + r;
                sOut[orow * 136 + colc] = f2bf(acc[nt][r] + b1r[nt]);
            }
        }
        __syncthreads();
        #pragma unroll
        for (int i = 0; i < 4; ++i) {
            int idx = t + i * 256;      // 1024 chunks of 16B
            int r   = idx >> 4;
            int ch  = idx & 15;
            int grow = rbase + r;
            if (grow < nrows)
                *(uint4*)(P + (size_t)grow * HH + ch * 8) =
                    *(const uint4*)(sOut + r * 136 + ch * 8);
        }
    }
}

// ---------------- edge kernel: out[e] = relu(Pu[u]+Pi[i]) . W2 + b2  (P bf16, b1 folded) ------
// 16 lanes per edge, 16B (8 bf16) per lane.
__global__ __launch_bounds__(256) void edge_bf16_kernel(
    const unsigned short* __restrict__ Pu, const unsigned short* __restrict__ Pi,
    const int* __restrict__ row, const int* __restrict__ col,
    const float* __restrict__ W2, const float* __restrict__ b2,
    float* __restrict__ out, int E)
{
    const int lane16 = threadIdx.x & 15;
    const int gid    = (blockIdx.x * blockDim.x + threadIdx.x) >> 4;
    const int stride = (gridDim.x * blockDim.x) >> 4;
    const int c0     = lane16 * 8;

    float w2r[8];
    #pragma unroll
    for (int j = 0; j < 8; ++j) w2r[j] = W2[c0 + j];
    const float b2s = b2[0];

    for (int e = gid; e < E; e += stride) {
        int u  = row[e];
        int it = col[e];
        uint4 pu = *(const uint4*)(Pu + (size_t)u  * HH + c0);
        uint4 pi = *(const uint4*)(Pi + (size_t)it * HH + c0);
        unsigned puw[4] = {pu.x, pu.y, pu.z, pu.w};
        unsigned piw[4] = {pi.x, pi.y, pi.z, pi.w};
        float p = 0.f;
        #pragma unroll
        for (int q = 0; q < 4; ++q) {
            float a0 = __builtin_bit_cast(float, puw[q] << 16);
            float a1 = __builtin_bit_cast(float, puw[q] & 0xFFFF0000u);
            float c0f = __builtin_bit_cast(float, piw[q] << 16);
            float c1f = __builtin_bit_cast(float, piw[q] & 0xFFFF0000u);
            float h0 = fmaxf(a0 + c0f, 0.f);
            float h1 = fmaxf(a1 + c1f, 0.f);
            p = fmaf(h0, w2r[2 * q],     p);
            p = fmaf(h1, w2r[2 * q + 1], p);
        }
        #pragma unroll
        for (int m = 8; m >= 1; m >>= 1)
            p += __shfl_xor(p, m, 64);
        if (lane16 == 0) out[e] = p + b2s;
    }
}

// ---------------- fallback (no workspace): direct per-edge fp32 compute ----------------
__global__ __launch_bounds__(256) void edge_direct_kernel(
    const float* __restrict__ zu, const float* __restrict__ zi,
    const int* __restrict__ row, const int* __restrict__ col,
    const float* __restrict__ W1, const float* __restrict__ b1,
    const float* __restrict__ W2, const float* __restrict__ b2,
    float* __restrict__ out, int E)
{
    const int lane   = threadIdx.x & 31;
    const int gid    = (blockIdx.x * blockDim.x + threadIdx.x) >> 5;
    const int stride = (gridDim.x * blockDim.x) >> 5;
    const int c0     = lane * 4;

    const float4 b1v = *(const float4*)(b1 + c0);
    const float4 w2v = *(const float4*)(W2 + c0);
    const float  b2s = b2[0];

    for (int e = gid; e < E; e += stride) {
        int u  = row[e];
        int it = col[e];
        const float* zur = zu + (size_t)u  * HH;
        const float* zir = zi + (size_t)it * HH;
        float4 acc = b1v;
        for (int k = 0; k < HH; ++k) {
            float  zk = zur[k];
            float4 w  = *(const float4*)(W1 + (size_t)k * HH + c0);
            acc.x = fmaf(zk, w.x, acc.x);
            acc.y = fmaf(zk, w.y, acc.y);
            acc.z = fmaf(zk, w.z, acc.z);
            acc.w = fmaf(zk, w.w, acc.w);
        }
        for (int k = 0; k < HH; ++k) {
            float  zk = zir[k];
            float4 w  = *(const float4*)(W1 + (size_t)(HH + k) * HH + c0);
            acc.x = fmaf(zk, w.x, acc.x);
            acc.y = fmaf(zk, w.y, acc.y);
            acc.z = fmaf(zk, w.z, acc.z);
            acc.w = fmaf(zk, w.w, acc.w);
        }
        float p = fmaxf(acc.x, 0.f) * w2v.x;
        p = fmaf(fmaxf(acc.y, 0.f), w2v.y, p);
        p = fmaf(fmaxf(acc.z, 0.f), w2v.z, p);
        p = fmaf(fmaxf(acc.w, 0.f), w2v.w, p);
        #pragma unroll
        for (int m = 16; m >= 1; m >>= 1)
            p += __shfl_xor(p, m, 64);
        if (lane == 0) out[e] = p + b2s;
    }
}

extern "C" void kernel_launch(void* const* d_in, const int* in_sizes, int n_in,
                              void* d_out, int out_size, void* d_ws, size_t ws_size,
                              hipStream_t stream)
{
    const float* z_user = (const float*)d_in[0];
    const float* z_item = (const float*)d_in[1];
    const int*   row    = (const int*)d_in[2];
    const int*   col    = (const int*)d_in[3];
    const float* W1     = (const float*)d_in[4];
    const float* b1     = (const float*)d_in[5];
    const float* W2     = (const float*)d_in[6];
    const float* b2     = (const float*)d_in[7];
    float*       out    = (float*)d_out;

    const int n_user = in_sizes[0] / HH;
    const int n_item = in_sizes[1] / HH;
    const int E      = in_sizes[2];

    const size_t need = ((size_t)n_user + (size_t)n_item) * HH * sizeof(unsigned short);
    if (ws_size >= need) {
        unsigned short* Pu = (unsigned short*)d_ws;
        unsigned short* Pi = Pu + (size_t)n_user * HH;
        project_mfma_kernel<<<768, 256, 0, stream>>>(z_user, W1, b1, 1, Pu, n_user);
        project_mfma_kernel<<<768, 256, 0, stream>>>(z_item, W1 + HH * HH, b1, 0, Pi, n_item);
        edge_bf16_kernel<<<2048, 256, 0, stream>>>(Pu, Pi, row, col, W2, b2, out, E);
    } else {
        edge_direct_kernel<<<2048, 256, 0, stream>>>(z_user, z_item, row, col, W1, b1, W2, b2, out, E);
    }
}

// Round 3
// 106.055 us; speedup vs baseline: 2.1414x; 1.0626x over previous
//
#include <hip/hip_runtime.h>

#define HH 128

typedef __attribute__((ext_vector_type(8))) short bf16x8;
typedef __attribute__((ext_vector_type(4))) float f32x4;

__device__ inline unsigned short f2bf(float f) {
    unsigned u = __builtin_bit_cast(unsigned, f);
    u += 0x7FFF + ((u >> 16) & 1);   // round to nearest even
    return (unsigned short)(u >> 16);
}

// ---------------- fused MFMA projection: both tables in one launch ----------------
// Block = 256 threads (4 waves); tile = 64 rows x 128 cols; K = 128.
// Blocks [0, ublocks) -> user table (bias folded), [ublocks, ublocks+iblocks) -> item.
// Each block handles exactly 2 consecutive row tiles of its table.
__global__ __launch_bounds__(256) void project_both_kernel(
    const float* __restrict__ Zu, const float* __restrict__ Zi,
    const float* __restrict__ W1, const float* __restrict__ b1,
    unsigned short* __restrict__ Pu, unsigned short* __restrict__ Pi,
    int n_user, int n_item, int ublocks)
{
    // sWt: element (c,k) at c*128 + ((k>>3)^(c&15))*8 + (k&7)   (ushort)
    __shared__ unsigned short sWt[128 * 128];    // 32 KB
    __shared__ unsigned short sOut[64 * 136];    // 17 KB, stride 136

    const bool isUser = ((int)blockIdx.x < ublocks);
    const float* __restrict__ Z = isUser ? Zu : Zi;
    const float* __restrict__ W = isUser ? W1 : (W1 + HH * HH);
    unsigned short* __restrict__ P = isUser ? Pu : Pi;
    const int nrows  = isUser ? n_user : n_item;
    const int ntiles = (nrows + 63) >> 6;
    const int tbase  = (isUser ? (int)blockIdx.x : ((int)blockIdx.x - ublocks)) * 2;

    const int t    = threadIdx.x;
    const int wave = t >> 6;
    const int lane = t & 63;
    const int l16  = lane & 15;
    const int lk8  = (lane >> 4) * 8;

    // ---- stage W^T (this table's half) as bf16 with chunk swizzle ----
    #pragma unroll 4
    for (int i = 0; i < 16; ++i) {
        int idx = t + i * 256;          // 0..4095 float4 chunks
        int k   = idx >> 5;             // 128 k-rows, 32 float4 each
        int c4  = (idx & 31) * 4;
        float4 w = *(const float4*)(W + (size_t)k * HH + c4);
        float wv[4] = {w.x, w.y, w.z, w.w};
        #pragma unroll
        for (int j = 0; j < 4; ++j) {
            int c = c4 + j;
            sWt[c * 128 + (((k >> 3) ^ (c & 15)) << 3) + (k & 7)] = f2bf(wv[j]);
        }
    }

    // per-lane bias (col = nt*16 + l16); only user table folds b1
    float b1r[8];
    #pragma unroll
    for (int nt = 0; nt < 8; ++nt)
        b1r[nt] = isUser ? b1[nt * 16 + l16] : 0.f;

    __syncthreads();

    #pragma unroll 1
    for (int s = 0; s < 2; ++s) {
        const int tile = tbase + s;
        if (tile >= ntiles) break;
        const int rbase = tile << 6;

        f32x4 acc[8];
        #pragma unroll
        for (int nt = 0; nt < 8; ++nt) acc[nt] = (f32x4)0.f;

        int m = rbase + wave * 16 + l16;
        if (m > nrows - 1) m = nrows - 1;          // clamp tail (stores guarded)
        const float* Zrow = Z + (size_t)m * HH;

        #pragma unroll
        for (int kk = 0; kk < 4; ++kk) {
            float4 z0 = *(const float4*)(Zrow + kk * 32 + lk8);
            float4 z1 = *(const float4*)(Zrow + kk * 32 + lk8 + 4);
            bf16x8 a;
            a[0] = (short)f2bf(z0.x); a[1] = (short)f2bf(z0.y);
            a[2] = (short)f2bf(z0.z); a[3] = (short)f2bf(z0.w);
            a[4] = (short)f2bf(z1.x); a[5] = (short)f2bf(z1.y);
            a[6] = (short)f2bf(z1.z); a[7] = (short)f2bf(z1.w);

            const int chunkSw = ((kk * 4 + (lane >> 4)) ^ l16) << 3;
            #pragma unroll
            for (int nt = 0; nt < 8; ++nt) {
                int c = nt * 16 + l16;
                bf16x8 b = *(const bf16x8*)(sWt + c * 128 + chunkSw);
                acc[nt] = __builtin_amdgcn_mfma_f32_16x16x32_bf16(a, b, acc[nt], 0, 0, 0);
            }
        }

        __syncthreads();   // sOut safe to overwrite
        #pragma unroll
        for (int nt = 0; nt < 8; ++nt) {
            int colc = nt * 16 + l16;
            #pragma unroll
            for (int r = 0; r < 4; ++r) {
                int orow = wave * 16 + (lane >> 4) * 4 + r;
                sOut[orow * 136 + colc] = f2bf(acc[nt][r] + b1r[nt]);
            }
        }
        __syncthreads();
        #pragma unroll
        for (int i = 0; i < 4; ++i) {
            int idx = t + i * 256;      // 1024 chunks of 16B
            int r   = idx >> 4;
            int ch  = idx & 15;
            int grow = rbase + r;
            if (grow < nrows)
                *(uint4*)(P + (size_t)grow * HH + ch * 8) =
                    *(const uint4*)(sOut + r * 136 + ch * 8);
        }
    }
}

// ---------------- edge kernel: out[e] = relu(Pu[u]+Pi[i]) . W2 + b2  (P bf16, b1 folded) ------
// 16 lanes per edge, 16B per lane; 2 edges per iteration for MLP.
__global__ __launch_bounds__(256) void edge_bf16_kernel(
    const unsigned short* __restrict__ Pu, const unsigned short* __restrict__ Pi,
    const int* __restrict__ row, const int* __restrict__ col,
    const float* __restrict__ W2, const float* __restrict__ b2,
    float* __restrict__ out, int E)
{
    const int lane16 = threadIdx.x & 15;
    const int gid    = (blockIdx.x * blockDim.x + threadIdx.x) >> 4;
    const int stride = (gridDim.x * blockDim.x) >> 4;
    const int c0     = lane16 * 8;

    float w2r[8];
    #pragma unroll
    for (int j = 0; j < 8; ++j) w2r[j] = W2[c0 + j];
    const float b2s = b2[0];

    int e = gid;
    for (; e + stride < E; e += 2 * stride) {
        const int e2 = e + stride;
        int u0 = row[e],  i0 = col[e];
        int u1 = row[e2], i1 = col[e2];
        uint4 pu0 = *(const uint4*)(Pu + (size_t)u0 * HH + c0);
        uint4 pi0 = *(const uint4*)(Pi + (size_t)i0 * HH + c0);
        uint4 pu1 = *(const uint4*)(Pu + (size_t)u1 * HH + c0);
        uint4 pi1 = *(const uint4*)(Pi + (size_t)i1 * HH + c0);

        unsigned a0[4] = {pu0.x, pu0.y, pu0.z, pu0.w};
        unsigned b0[4] = {pi0.x, pi0.y, pi0.z, pi0.w};
        unsigned a1[4] = {pu1.x, pu1.y, pu1.z, pu1.w};
        unsigned b1w[4] = {pi1.x, pi1.y, pi1.z, pi1.w};

        float p0 = 0.f, p1 = 0.f;
        #pragma unroll
        for (int q = 0; q < 4; ++q) {
            float x0 = __builtin_bit_cast(float, a0[q] << 16);
            float x1 = __builtin_bit_cast(float, a0[q] & 0xFFFF0000u);
            float y0 = __builtin_bit_cast(float, b0[q] << 16);
            float y1 = __builtin_bit_cast(float, b0[q] & 0xFFFF0000u);
            p0 = fmaf(fmaxf(x0 + y0, 0.f), w2r[2 * q],     p0);
            p0 = fmaf(fmaxf(x1 + y1, 0.f), w2r[2 * q + 1], p0);
            float u0f = __builtin_bit_cast(float, a1[q] << 16);
            float u1f = __builtin_bit_cast(float, a1[q] & 0xFFFF0000u);
            float v0f = __builtin_bit_cast(float, b1w[q] << 16);
            float v1f = __builtin_bit_cast(float, b1w[q] & 0xFFFF0000u);
            p1 = fmaf(fmaxf(u0f + v0f, 0.f), w2r[2 * q],     p1);
            p1 = fmaf(fmaxf(u1f + v1f, 0.f), w2r[2 * q + 1], p1);
        }
        #pragma unroll
        for (int m = 8; m >= 1; m >>= 1) {
            p0 += __shfl_xor(p0, m, 64);
            p1 += __shfl_xor(p1, m, 64);
        }
        if (lane16 == 0) { out[e] = p0 + b2s; out[e2] = p1 + b2s; }
    }
    if (e < E) {
        int u = row[e], it = col[e];
        uint4 pu = *(const uint4*)(Pu + (size_t)u  * HH + c0);
        uint4 pi = *(const uint4*)(Pi + (size_t)it * HH + c0);
        unsigned a[4] = {pu.x, pu.y, pu.z, pu.w};
        unsigned b[4] = {pi.x, pi.y, pi.z, pi.w};
        float p = 0.f;
        #pragma unroll
        for (int q = 0; q < 4; ++q) {
            float x0 = __builtin_bit_cast(float, a[q] << 16);
            float x1 = __builtin_bit_cast(float, a[q] & 0xFFFF0000u);
            float y0 = __builtin_bit_cast(float, b[q] << 16);
            float y1 = __builtin_bit_cast(float, b[q] & 0xFFFF0000u);
            p = fmaf(fmaxf(x0 + y0, 0.f), w2r[2 * q],     p);
            p = fmaf(fmaxf(x1 + y1, 0.f), w2r[2 * q + 1], p);
        }
        #pragma unroll
        for (int m = 8; m >= 1; m >>= 1)
            p += __shfl_xor(p, m, 64);
        if (lane16 == 0) out[e] = p + b2s;
    }
}

// ---------------- fallback (no workspace): direct per-edge fp32 compute ----------------
__global__ __launch_bounds__(256) void edge_direct_kernel(
    const float* __restrict__ zu, const float* __restrict__ zi,
    const int* __restrict__ row, const int* __restrict__ col,
    const float* __restrict__ W1, const float* __restrict__ b1,
    const float* __restrict__ W2, const float* __restrict__ b2,
    float* __restrict__ out, int E)
{
    const int lane   = threadIdx.x & 31;
    const int gid    = (blockIdx.x * blockDim.x + threadIdx.x) >> 5;
    const int stride = (gridDim.x * blockDim.x) >> 5;
    const int c0     = lane * 4;

    const float4 b1v = *(const float4*)(b1 + c0);
    const float4 w2v = *(const float4*)(W2 + c0);
    const float  b2s = b2[0];

    for (int e = gid; e < E; e += stride) {
        int u  = row[e];
        int it = col[e];
        const float* zur = zu + (size_t)u  * HH;
        const float* zir = zi + (size_t)it * HH;
        float4 acc = b1v;
        for (int k = 0; k < HH; ++k) {
            float  zk = zur[k];
            float4 w  = *(const float4*)(W1 + (size_t)k * HH + c0);
            acc.x = fmaf(zk, w.x, acc.x);
            acc.y = fmaf(zk, w.y, acc.y);
            acc.z = fmaf(zk, w.z, acc.z);
            acc.w = fmaf(zk, w.w, acc.w);
        }
        for (int k = 0; k < HH; ++k) {
            float  zk = zir[k];
            float4 w  = *(const float4*)(W1 + (size_t)(HH + k) * HH + c0);
            acc.x = fmaf(zk, w.x, acc.x);
            acc.y = fmaf(zk, w.y, acc.y);
            acc.z = fmaf(zk, w.z, acc.z);
            acc.w = fmaf(zk, w.w, acc.w);
        }
        float p = fmaxf(acc.x, 0.f) * w2v.x;
        p = fmaf(fmaxf(acc.y, 0.f), w2v.y, p);
        p = fmaf(fmaxf(acc.z, 0.f), w2v.z, p);
        p = fmaf(fmaxf(acc.w, 0.f), w2v.w, p);
        #pragma unroll
        for (int m = 16; m >= 1; m >>= 1)
            p += __shfl_xor(p, m, 64);
        if (lane == 0) out[e] = p + b2s;
    }
}

extern "C" void kernel_launch(void* const* d_in, const int* in_sizes, int n_in,
                              void* d_out, int out_size, void* d_ws, size_t ws_size,
                              hipStream_t stream)
{
    const float* z_user = (const float*)d_in[0];
    const float* z_item = (const float*)d_in[1];
    const int*   row    = (const int*)d_in[2];
    const int*   col    = (const int*)d_in[3];
    const float* W1     = (const float*)d_in[4];
    const float* b1     = (const float*)d_in[5];
    const float* W2     = (const float*)d_in[6];
    const float* b2     = (const float*)d_in[7];
    float*       out    = (float*)d_out;

    const int n_user = in_sizes[0] / HH;
    const int n_item = in_sizes[1] / HH;
    const int E      = in_sizes[2];

    const size_t need = ((size_t)n_user + (size_t)n_item) * HH * sizeof(unsigned short);
    if (ws_size >= need) {
        unsigned short* Pu = (unsigned short*)d_ws;
        unsigned short* Pi = Pu + (size_t)n_user * HH;
        const int utiles  = (n_user + 63) >> 6;
        const int itiles  = (n_item + 63) >> 6;
        const int ublocks = (utiles + 1) >> 1;   // 2 tiles per block
        const int iblocks = (itiles + 1) >> 1;
        project_both_kernel<<<ublocks + iblocks, 256, 0, stream>>>(
            z_user, z_item, W1, b1, Pu, Pi, n_user, n_item, ublocks);
        edge_bf16_kernel<<<2048, 256, 0, stream>>>(Pu, Pi, row, col, W2, b2, out, E);
    } else {
        edge_direct_kernel<<<2048, 256, 0, stream>>>(z_user, z_item, row, col, W1, b1, W2, b2, out, E);
    }
}